// Round 3
// baseline (1060.588 us; speedup 1.0000x reference)
//
#include <hip/hip_runtime.h>

#define N_NODES 50000
#define N_EDGES 800000
#define F 64
#define EDIM 16
#define NUM_CONV 3
#define NEG_SLOPE 0.01f

// ---------------- CSR build: histogram over dst ----------------
__global__ __launch_bounds__(256) void hist_kernel(const int* __restrict__ ei,
                                                   int* __restrict__ count) {
    for (int e = blockIdx.x * blockDim.x + threadIdx.x; e < N_EDGES;
         e += gridDim.x * blockDim.x)
        atomicAdd(&count[ei[N_EDGES + e]], 1);
}

// single-block exclusive scan; writes rowptr[N+1] and a working copy (cursor)
__global__ __launch_bounds__(1024) void scan_kernel(const int* __restrict__ count,
                                                    int* __restrict__ rowptr,
                                                    int* __restrict__ cursor) {
    __shared__ int buf[1024];
    const int tid = threadIdx.x;
    int run = 0;
    for (int base = 0; base < N_NODES; base += 1024) {
        int i = base + tid;
        int v = (i < N_NODES) ? count[i] : 0;
        buf[tid] = v;
        __syncthreads();
        for (int off = 1; off < 1024; off <<= 1) {
            int t = (tid >= off) ? buf[tid - off] : 0;
            __syncthreads();
            buf[tid] += t;
            __syncthreads();
        }
        int excl = buf[tid] - v;
        if (i < N_NODES) { rowptr[i] = run + excl; cursor[i] = run + excl; }
        run += buf[1023];
        __syncthreads();
    }
    if (tid == 0) rowptr[N_NODES] = run;
}

// scatter edges into CSR buckets: pairs[pos] = (src, edge_id)
__global__ __launch_bounds__(256) void scatter_kernel(const int* __restrict__ ei,
                                                      int* __restrict__ cursor,
                                                      int2* __restrict__ pairs) {
    for (int e = blockIdx.x * blockDim.x + threadIdx.x; e < N_EDGES;
         e += gridDim.x * blockDim.x) {
        int d = ei[N_EDGES + e];
        int pos = atomicAdd(&cursor[d], 1);
        pairs[pos] = make_int2(ei[e], e);
    }
}

// ---------------- fuse readout weights: Wf = W1@W2 [64,2], bf = b1@W2 + b2 ----------------
__global__ void fuse_weights_kernel(
    const float* __restrict__ W1, const float* __restrict__ b1,
    const float* __restrict__ W2, const float* __restrict__ b2,
    float* __restrict__ Wf, float* __restrict__ bf) {
    const int t = threadIdx.x;     // 128 threads
    const int i = t >> 1;
    const int j = t & 1;
    float acc = 0.f;
    for (int k = 0; k < 128; ++k) acc += W1[i * 128 + k] * W2[k * 2 + j];
    Wf[i * 2 + j] = acc;
    if (i == 0) {
        float accb = b2[j];
        for (int k = 0; k < 128; ++k) accb += b1[k] * W2[k * 2 + j];
        bf[j] = accb;
    }
}

// ---------------- fused GINE layer (pull mode), wave per dst node ----------------
// aggr_n = sum_{e: dst=n} relu(h[src_e] + ea[e]@We + be)
// t = h[n] + aggr; hout = leaky(t@Wn + bn); last layer: out = leaky(...)@Wf + bf
template <bool LAST>
__global__ __launch_bounds__(256) void conv_kernel(
    const float* __restrict__ h,
    const int* __restrict__ rowptr,
    const int2* __restrict__ pairs,
    const float* __restrict__ ea,
    const float* __restrict__ We, const float* __restrict__ be,
    const float* __restrict__ Wn, const float* __restrict__ bn,
    const float* __restrict__ Wf, const float* __restrict__ bf,
    float* __restrict__ hout, float* __restrict__ out) {
    __shared__ float WsE[EDIM * F];
    __shared__ float WnS[F * F];
    __shared__ float bsE[F], bsN[F];
    __shared__ float WfS[F * 2];
    __shared__ float bfS[2];
    for (int i = threadIdx.x; i < EDIM * F; i += 256) WsE[i] = We[i];
    for (int i = threadIdx.x; i < F * F; i += 256) WnS[i] = Wn[i];
    if (threadIdx.x < F) { bsE[threadIdx.x] = be[threadIdx.x]; bsN[threadIdx.x] = bn[threadIdx.x]; }
    if (LAST) {
        if (threadIdx.x < F * 2) WfS[threadIdx.x] = Wf[threadIdx.x];
        if (threadIdx.x < 2) bfS[threadIdx.x] = bf[threadIdx.x];
    }
    __syncthreads();

    const int lane = threadIdx.x & 63;
    const int wid  = threadIdx.x >> 6;
    const int wstride = gridDim.x * 4;

    for (int n = blockIdx.x * 4 + wid; n < N_NODES; n += wstride) {
        const int start = rowptr[n], end = rowptr[n + 1];
        float aggr = 0.f;
        for (int j = start; j < end; ++j) {
            int2 p = pairs[j];                                  // (src, e)
            float av = ea[(size_t)p.y * EDIM + (lane & 15)];    // lanes 0-15 hold ea[e][k]
            float hs = h[(size_t)p.x * F + lane];
            float acc = bsE[lane];
#pragma unroll
            for (int k = 0; k < EDIM; ++k)
                acc = fmaf(__shfl(av, k), WsE[k * F + lane], acc);
            float m = hs + acc;
            aggr += (m > 0.f ? m : 0.f);                        // ReLU
        }
        float t = h[(size_t)n * F + lane] + aggr;
        float acc = bsN[lane];
#pragma unroll
        for (int k = 0; k < F; ++k)
            acc = fmaf(__shfl(t, k), WnS[k * F + lane], acc);
        acc = acc >= 0.f ? acc : NEG_SLOPE * acc;               // LeakyReLU
        if (!LAST) {
            hout[(size_t)n * F + lane] = acc;
        } else {
            float v0 = acc * WfS[lane * 2 + 0];
            float v1 = acc * WfS[lane * 2 + 1];
#pragma unroll
            for (int off = 32; off; off >>= 1) {
                v0 += __shfl_down(v0, off);
                v1 += __shfl_down(v1, off);
            }
            if (lane == 0) {
                out[(size_t)n * 2 + 0] = v0 + bfS[0];
                out[(size_t)n * 2 + 1] = v1 + bfS[1];
            }
        }
    }
}

extern "C" void kernel_launch(void* const* d_in, const int* in_sizes, int n_in,
                              void* d_out, int out_size, void* d_ws, size_t ws_size,
                              hipStream_t stream) {
    const float* x  = (const float*)d_in[0];
    const int*   ei = (const int*)d_in[1];       // int32 per harness contract
    const float* ea = (const float*)d_in[2];
    const float* Wn = (const float*)d_in[3];
    const float* bn = (const float*)d_in[4];
    const float* We = (const float*)d_in[5];     // [3,16,64]
    const float* be = (const float*)d_in[6];     // [3,64]
    const float* W1 = (const float*)d_in[7];
    const float* b1 = (const float*)d_in[8];
    const float* W2 = (const float*)d_in[9];
    const float* b2 = (const float*)d_in[10];
    float* out = (float*)d_out;

    char* wsb = (char*)d_ws;
    int*  count  = (int*)wsb;                         wsb += sizeof(int) * N_NODES;
    int*  rowptr = (int*)wsb;                         wsb += sizeof(int) * (N_NODES + 1);
    int*  cursor = (int*)wsb;                         wsb += sizeof(int) * N_NODES;
    int2* pairs  = (int2*)wsb;                        wsb += sizeof(int2) * N_EDGES;
    float* hA    = (float*)wsb;                       wsb += sizeof(float) * (size_t)N_NODES * F;
    float* hB    = (float*)wsb;                       wsb += sizeof(float) * (size_t)N_NODES * F;
    float* Wf    = (float*)wsb;                       wsb += sizeof(float) * F * 2;
    float* bf    = (float*)wsb;

    // independent of CSR build
    fuse_weights_kernel<<<1, 128, 0, stream>>>(W1, b1, W2, b2, Wf, bf);

    // CSR build (edge_index is layer-invariant: build once, use 3x)
    hipMemsetAsync(count, 0, sizeof(int) * N_NODES, stream);
    hist_kernel<<<1024, 256, 0, stream>>>(ei, count);
    scan_kernel<<<1, 1024, 0, stream>>>(count, rowptr, cursor);
    scatter_kernel<<<1024, 256, 0, stream>>>(ei, cursor, pairs);

    // layer 0: x -> hA ; layer 1: hA -> hB ; layer 2 (last): hB -> out
    conv_kernel<false><<<1024, 256, 0, stream>>>(x, rowptr, pairs, ea,
        We + 0 * EDIM * F, be + 0 * F, Wn, bn, Wf, bf, hA, out);
    conv_kernel<false><<<1024, 256, 0, stream>>>(hA, rowptr, pairs, ea,
        We + 1 * EDIM * F, be + 1 * F, Wn, bn, Wf, bf, hB, out);
    conv_kernel<true><<<1024, 256, 0, stream>>>(hB, rowptr, pairs, ea,
        We + 2 * EDIM * F, be + 2 * F, Wn, bn, Wf, bf, nullptr, out);
}